// Round 5
// baseline (157.854 us; speedup 1.0000x reference)
//
#include <hip/hip_runtime.h>

#define NC 20
#define CH 30

constexpr int WAVE = 64;
constexpr int CELLS_PER_TILE = 64;                 // one cell per lane per tile
constexpr int TILE_V4 = CELLS_PER_TILE * CH / 4;   // 480 float4 chunks per array
constexpr int WLOADS = 8;                          // 8 wave-loads (480 real + 32 clamped pad)
constexpr int LDS_FLOATS = WLOADS * WAVE * 4;      // 2048 floats = 8 KB per array per buffer
constexpr int NBLOCKS = 1280;                      // 5 blocks/CU x 32,768 B = 160 KB LDS exactly

// Per-cell YOLOv1 loss (validated rounds 1-4, absmax 0.0). 8B-aligned inputs.
__device__ __forceinline__ float cell_loss(const float* __restrict__ tf,
                                           const float* __restrict__ pf) {
    const float2* t2 = (const float2*)tf;
    const float2* p2 = (const float2*)pf;

    float cl = 0.f;
#pragma unroll
    for (int c = 0; c < NC / 2; ++c) {
        float2 a = t2[c], b = p2[c];
        float d0 = a.x - b.x, d1 = a.y - b.y;
        cl = fmaf(d0, d0, cl);
        cl = fmaf(d1, d1, cl);
    }
    float2 v10 = t2[10], v11 = t2[11];
    float th = tf[24];
    float obj = v10.x, tx = v10.y, ty = v11.x, tw = v11.y;
    float2 q10 = p2[10], q11 = p2[11], q12 = p2[12], q13 = p2[13], q14 = p2[14];
    float conf0 = q10.x, px0 = q10.y, py0 = q11.x, pw0 = q11.y, ph0 = q12.x;
    float conf1 = q12.y, px1 = q13.x, py1 = q13.y, pw1 = q14.x, ph1 = q14.y;

    float t_x1 = tx - tw * 0.5f, t_x2 = tx + tw * 0.5f;
    float t_y1 = ty - th * 0.5f, t_y2 = ty + th * 0.5f;
    float ta = fabsf((t_x2 - t_x1) * (t_y2 - t_y1));

    float b_x1 = px0 - pw0 * 0.5f, b_x2 = px0 + pw0 * 0.5f;
    float b_y1 = py0 - ph0 * 0.5f, b_y2 = py0 + ph0 * 0.5f;
    float ix = fmaxf(fminf(t_x2, b_x2) - fmaxf(t_x1, b_x1), 0.f);
    float iy = fmaxf(fminf(t_y2, b_y2) - fmaxf(t_y1, b_y1), 0.f);
    float inter0 = ix * iy;
    float a0 = fabsf((b_x2 - b_x1) * (b_y2 - b_y1));
    float iou0 = inter0 * __builtin_amdgcn_rcpf(ta + a0 - inter0 + 1e-6f);

    float c_x1 = px1 - pw1 * 0.5f, c_x2 = px1 + pw1 * 0.5f;
    float c_y1 = py1 - ph1 * 0.5f, c_y2 = py1 + ph1 * 0.5f;
    float jx = fmaxf(fminf(t_x2, c_x2) - fmaxf(t_x1, c_x1), 0.f);
    float jy = fmaxf(fminf(t_y2, c_y2) - fmaxf(t_y1, c_y1), 0.f);
    float inter1 = jx * jy;
    float a1 = fabsf((c_x2 - c_x1) * (c_y2 - c_y1));
    float iou1 = inter1 * __builtin_amdgcn_rcpf(ta + a1 - inter1 + 1e-6f);

    bool sel1 = iou1 > iou0;
    float conf = sel1 ? conf1 : conf0;
    float piou = sel1 ? iou1 : iou0;
    float px = sel1 ? px1 : px0;
    float py = sel1 ? py1 : py0;
    float pw = sel1 ? pw1 : pw0;
    float ph = sel1 ? ph1 : ph0;

    float dx = tx - px, dy = ty - py;
    float xy = dx * dx + dy * dy;
    float sgw = (pw > 0.f) ? 1.f : ((pw < 0.f) ? -1.f : 0.f);
    float sgh = (ph > 0.f) ? 1.f : ((ph < 0.f) ? -1.f : 0.f);
    float dw = __builtin_amdgcn_sqrtf(tw) - sgw * __builtin_amdgcn_sqrtf(fabsf(pw) + 1e-6f);
    float dh = __builtin_amdgcn_sqrtf(th) - sgh * __builtin_amdgcn_sqrtf(fabsf(ph) + 1e-6f);
    float wh = dw * dw + dh * dh;
    float dob = piou - conf;

    return obj * (5.f * (xy + wh) + dob * dob + cl) + (1.f - obj) * (0.5f * conf * conf);
}

// Single-wave block, barrierless double-buffered streaming (R2 structure).
// Steady state: next tile's 16 loads stay in flight through each compute phase.
__global__ __launch_bounds__(WAVE) void yolo_main(
    const float* __restrict__ yt, const float* __restrict__ yp,
    float* __restrict__ partial, int ncells, int ntiles) {
    __shared__ float st[2][LDS_FLOATS];
    __shared__ float sp[2][LDS_FLOATS];

    const int lane = threadIdx.x;
    const long total_v4 = ((long)ncells * CH) / 4;
    const float4* gt = (const float4*)yt;
    const float4* gp = (const float4*)yp;

    const int b = blockIdx.x;
    const int tpb = ntiles / gridDim.x;
    const int rem = ntiles - tpb * gridDim.x;
    const int n = tpb + (b < rem ? 1 : 0);
    const int start = b * tpb + (b < rem ? b : rem);

    float acc = 0.f;

    // 8 wave-loads per array (480 real + 32 pad chunks). Fast path (every tile
    // except the globally last one): no per-lane clamp -> uniform base + lane
    // offset, compiler folds imm offsets, ~3x fewer VALU in the stage window.
    // Pad chunks read the next tile's head: L2 hit, ~0 extra HBM.
#define STAGE(BUF, TILE) do {                                                  \
    long _base = (long)(TILE) * TILE_V4;                                       \
    if (_base + WLOADS * WAVE <= total_v4) {                                   \
        const float4* _t = gt + _base + lane;                                  \
        const float4* _p = gp + _base + lane;                                  \
        _Pragma("unroll")                                                      \
        for (int _i = 0; _i < WLOADS; ++_i) {                                  \
            __builtin_amdgcn_global_load_lds(                                  \
                (const __attribute__((address_space(1))) void*)(_t + _i * WAVE),\
                (__attribute__((address_space(3))) void*)(&st[BUF][_i * WAVE * 4]),\
                16, 0, 0);                                                     \
            __builtin_amdgcn_global_load_lds(                                  \
                (const __attribute__((address_space(1))) void*)(_p + _i * WAVE),\
                (__attribute__((address_space(3))) void*)(&sp[BUF][_i * WAVE * 4]),\
                16, 0, 0);                                                     \
        }                                                                      \
    } else {                                                                   \
        _Pragma("unroll")                                                      \
        for (int _i = 0; _i < WLOADS; ++_i) {                                  \
            long _idx = _base + _i * WAVE + lane;                              \
            if (_idx >= total_v4) _idx = total_v4 - 1;                         \
            __builtin_amdgcn_global_load_lds(                                  \
                (const __attribute__((address_space(1))) void*)(gt + _idx),   \
                (__attribute__((address_space(3))) void*)(&st[BUF][_i * WAVE * 4]),\
                16, 0, 0);                                                     \
            __builtin_amdgcn_global_load_lds(                                  \
                (const __attribute__((address_space(1))) void*)(gp + _idx),   \
                (__attribute__((address_space(3))) void*)(&sp[BUF][_i * WAVE * 4]),\
                16, 0, 0);                                                     \
        }                                                                      \
    }                                                                          \
} while (0)

    if (n > 0) STAGE(0, start);
    if (n > 1) STAGE(1, start + 1);

    for (int t = 0; t < n; ++t) {
        const int cur = t & 1;
        if (t + 1 < n) {
            // wait for tile t only; tile t+1's 16 loads stay in flight
            asm volatile("s_waitcnt vmcnt(16)" ::: "memory");
        } else {
            asm volatile("s_waitcnt vmcnt(0)" ::: "memory");
        }
        __builtin_amdgcn_sched_barrier(0);

        const int cell = (start + t) * CELLS_PER_TILE + lane;
        if (cell < ncells)
            acc += cell_loss(&st[cur][lane * CH], &sp[cur][lane * CH]);

        if (t + 2 < n) {
            // all ds_reads of buf[cur] must have executed before gll overwrites it
            asm volatile("s_waitcnt lgkmcnt(0)" ::: "memory");
            __builtin_amdgcn_sched_barrier(0);
            STAGE(cur, start + t + 2);
        }
    }
#undef STAGE

    // single-wave reduction, plain store (no atomics, no d_out zeroing needed)
#pragma unroll
    for (int off = 32; off > 0; off >>= 1)
        acc += __shfl_down(acc, off, 64);
    if (lane == 0) partial[b] = acc;
}

__global__ __launch_bounds__(1024) void reduce_partials(
    const float* __restrict__ partial, float* __restrict__ out, int n) {
    __shared__ float ws[16];
    const int tid = threadIdx.x;
    float v = 0.f;
    for (int i = tid; i < n; i += 1024) v += partial[i];
#pragma unroll
    for (int off = 32; off > 0; off >>= 1)
        v += __shfl_down(v, off, 64);
    if ((tid & 63) == 0) ws[tid >> 6] = v;
    __syncthreads();
    if (tid == 0) {
        float s = 0.f;
#pragma unroll
        for (int w = 0; w < 16; ++w) s += ws[w];
        out[0] = s;
    }
}

extern "C" void kernel_launch(void* const* d_in, const int* in_sizes, int n_in,
                              void* d_out, int out_size, void* d_ws, size_t ws_size,
                              hipStream_t stream) {
    const float* yt = (const float*)d_in[0];
    const float* yp = (const float*)d_in[1];
    float* partial = (float*)d_ws;
    float* out = (float*)d_out;

    const int ncells = in_sizes[0] / CH;                                // 3,211,264
    const int ntiles = (ncells + CELLS_PER_TILE - 1) / CELLS_PER_TILE;  // 50,176

    const int nb = NBLOCKS < ntiles ? NBLOCKS : ntiles;
    yolo_main<<<nb, WAVE, 0, stream>>>(yt, yp, partial, ncells, ntiles);
    reduce_partials<<<1, 1024, 0, stream>>>(partial, out, nb);
}